// Round 9
// baseline (266.605 us; speedup 1.0000x reference)
//
#include <hip/hip_runtime.h>
#include <hip/hip_bf16.h>

#define N_NODES 50000
#define N_EDGES 1600000
#define EPB 4096              // edges per binning block
#define NB_A ((N_EDGES + EPB - 1) / EPB)   // 391 edge-chunk blocks
#define NBUCK2 391            // ceil(50000/128) buckets of 128 nodes
#define BSHIFT 7
#define BMASK 127
#define CAP 8064              // slots per bucket (mean 4096, sigma 64 -> 62 sigma)

typedef short bf16x8 __attribute__((ext_vector_type(8)));
typedef float f32x4  __attribute__((ext_vector_type(4)));
typedef float f32x2  __attribute__((ext_vector_type(2)));

#if __has_builtin(__builtin_amdgcn_exp2f)
#define EXP2(x) __builtin_amdgcn_exp2f(x)
#else
#define EXP2(x) exp2f(x)
#endif
#define LOG2E 1.44269504088896340736f

__device__ __forceinline__ float bf16_raw_to_f32(unsigned short u) {
    return __uint_as_float(((unsigned)u) << 16);
}
__device__ __forceinline__ unsigned short f32_to_bf16_raw(float v) {
    unsigned u = __float_as_uint(v);
    return (unsigned short)((u + 0x7fffu + ((u >> 16) & 1u)) >> 16);
}
__device__ __forceinline__ float load_elem(const void* p, size_t i, int f) {
    if (f) return ((const float*)p)[i];
    return bf16_raw_to_f32(((const unsigned short*)p)[i]);
}
// unpack 8 bf16 into 4 float2 pairs (pair k = dims {2k, 2k+1})
__device__ __forceinline__ void unpack8v(uint4 u, f32x2* f) {
    f[0] = (f32x2){__uint_as_float(u.x << 16), __uint_as_float(u.x & 0xffff0000u)};
    f[1] = (f32x2){__uint_as_float(u.y << 16), __uint_as_float(u.y & 0xffff0000u)};
    f[2] = (f32x2){__uint_as_float(u.z << 16), __uint_as_float(u.z & 0xffff0000u)};
    f[3] = (f32x2){__uint_as_float(u.w << 16), __uint_as_float(u.w & 0xffff0000u)};
}

// in-block dtype detect (R4-verified heuristic: fp32 storage looks like
// huge/NaN values when read as bf16 pairs).
__device__ __forceinline__ int block_detect(const unsigned short* w1raw) {
    __shared__ float red[256];
    int t = threadIdx.x;
    float mx = 0.f;
    for (int i = t * 2; i < 16384; i += 512) {
        float v = fabsf(bf16_raw_to_f32(w1raw[i]));
        if (!isnan(v)) mx = fmaxf(mx, v);
    }
    red[t] = mx;
    __syncthreads();
    for (int s = 128; s > 0; s >>= 1) {
        if (t < s) red[t] = fmaxf(red[t], red[t + s]);
        __syncthreads();
    }
    return (red[0] > 1e4f) ? 1 : 0;
}

#define WPAD 136

// ===== K1: prep (12 blocks) + detect (1 block) — tiny =====
__global__ void k1_prep_kernel(const void* __restrict__ W1,
                               const void* __restrict__ W2,
                               unsigned short* __restrict__ W1T,
                               unsigned short* __restrict__ W2T,
                               int* __restrict__ flag) {
    int bid = blockIdx.x;
    if (bid < 12) {
        const int f = block_detect((const unsigned short*)W1);
        int tid = threadIdx.x;
        if (bid < 8) {
            int n = bid * 16 + (tid & 15);
            int kb = (tid >> 4) * 8;
            for (int j = 0; j < 8; ++j)
                W1T[n * WPAD + kb + j] = f32_to_bf16_raw(load_elem(W1, (size_t)(kb + j) * 128 + n, f));
        } else {
            int n = (bid - 8) * 16 + (tid & 15);
            int kb = (tid >> 4) * 8;
            for (int j = 0; j < 8; ++j)
                W2T[n * WPAD + kb + j] = f32_to_bf16_raw(load_elem(W2, (size_t)(kb + j) * 64 + n, f));
        }
    } else {
        int f = block_detect((const unsigned short*)W1);
        if (threadIdx.x == 0) flag[0] = f;
    }
}

// ---- MFMA GEMM1 body (R9-proven), with row base for split launches ----
__device__ __forceinline__ void gemm1_body(const void* __restrict__ h,
                                           const unsigned short* __restrict__ W1T,
                                           unsigned short* __restrict__ feat1, int N,
                                           int f, int blk, int row_base) {
    int lane = threadIdx.x & 63;
    int rbase = row_base + blk * 64 + (threadIdx.x >> 6) * 16;
    int arow = rbase + (lane & 15);
    int arowc = min(arow, N - 1);
    int kb0 = (lane >> 4) * 8;

    f32x4 acc[8];
#pragma unroll
    for (int t = 0; t < 8; ++t) acc[t] = (f32x4){0.f, 0.f, 0.f, 0.f};

#pragma unroll
    for (int ks = 0; ks < 4; ++ks) {
        int kb = ks * 32 + kb0;
        bf16x8 afrag;
        if (f == 0) {
            afrag = *(const bf16x8*)((const unsigned short*)h + (size_t)arowc * 128 + kb);
        } else {
            const float* hp = (const float*)h + (size_t)arowc * 128 + kb;
#pragma unroll
            for (int j = 0; j < 8; ++j) afrag[j] = (short)f32_to_bf16_raw(hp[j]);
        }
#pragma unroll
        for (int t = 0; t < 8; ++t) {
            int n = t * 16 + (lane & 15);
            bf16x8 bfrag = *(const bf16x8*)(W1T + n * WPAD + kb);
            acc[t] = __builtin_amdgcn_mfma_f32_16x16x32_bf16(afrag, bfrag, acc[t], 0, 0, 0);
        }
    }
    int orow0 = rbase + (lane >> 4) * 4;
    int col = lane & 15;
#pragma unroll
    for (int t = 0; t < 8; ++t)
#pragma unroll
        for (int r = 0; r < 4; ++r) {
            int row = orow0 + r;
            if (row < N)
                feat1[(size_t)row * 128 + t * 16 + col] = f32_to_bf16_raw(acc[t][r]);
        }
}

#define G1LO 391                   // gemm1 blocks covering rows [0, 25024)
#define G1OFF (G1LO * 64)          // 25024

// ===== K2: fused [binA direct-reserve (391) | gemm1 rows 0..25023 (391)] =====
__global__ void k2_binA_gemm1lo_kernel(const int* __restrict__ src,
                                       const int* __restrict__ dst,
                                       int* __restrict__ bcur,
                                       unsigned* __restrict__ inter, int E,
                                       const void* __restrict__ h,
                                       const unsigned short* __restrict__ W1T,
                                       unsigned short* __restrict__ feat1, int N,
                                       const int* __restrict__ flag) {
    int bid = blockIdx.x;
    if (bid >= NB_A) {
        gemm1_body(h, W1T, feat1, N, *flag, bid - NB_A, 0);
        return;
    }
    __shared__ int hist[NBUCK2], gbase[NBUCK2], cur[NBUCK2];
    int t = threadIdx.x;
    for (int i = t; i < NBUCK2; i += 256) { hist[i] = 0; cur[i] = 0; }
    __syncthreads();
    int e0 = bid * EPB;
    for (int k = 0; k < 16; ++k) {
        int e = e0 + k * 256 + t;
        if (e < E) atomicAdd(&hist[dst[e] >> BSHIFT], 1);
    }
    __syncthreads();
    // direct slot reservation: bucket b occupies [b*CAP, (b+1)*CAP)
    for (int i = t; i < NBUCK2; i += 256) {
        int hv = hist[i];
        gbase[i] = hv ? (i * CAP + atomicAdd(&bcur[i], hv)) : 0;
    }
    __syncthreads();
    for (int k = 0; k < 16; ++k) {
        int e = e0 + k * 256 + t;
        if (e < E) {
            int d = dst[e];
            int b = d >> BSHIFT;
            int off = atomicAdd(&cur[b], 1);
            int slot = gbase[b] + off;
            if (slot < (b + 1) * CAP)   // overflow clamp (62-sigma, never in practice)
                inter[slot] = (unsigned)src[e] | ((unsigned)(d & BMASK) << 16);
        }
    }
}

// ===== K3: fused [binB in-place compact (391) | gemm1 rows 25024.. (391)] =====
__global__ void k3_binB_gemm1hi_kernel(unsigned* __restrict__ inter,   // also csr out
                                       const int* __restrict__ bcur,
                                       int* __restrict__ start,
                                       int* __restrict__ endv,
                                       int N, int E,
                                       const void* __restrict__ h,
                                       const unsigned short* __restrict__ W1T,
                                       unsigned short* __restrict__ feat1,
                                       const int* __restrict__ flag) {
    int bid = blockIdx.x;
    if (bid >= NBUCK2) {
        gemm1_body(h, W1T, feat1, N, *flag, bid - NBUCK2, G1OFF);
        return;
    }
    int b = bid;
    int node0 = b << BSHIFT;
    __shared__ int ibuf[CAP];
    __shared__ int hist[128];
    __shared__ int tmp[128];
    int t = threadIdx.x;
    int cnt = min(bcur[b], CAP);
    int gb = b * CAP;
    // stage bucket into LDS (enables in-place compaction: csr aliases inter)
    for (int i = t; i < cnt; i += 256) ibuf[i] = (int)inter[gb + i];
    if (t < 128) hist[t] = 0;
    __syncthreads();
    for (int i = t; i < cnt; i += 256) atomicAdd(&hist[((unsigned)ibuf[i]) >> 16], 1);
    __syncthreads();
    int own = (t < 128) ? hist[t] : 0;
    if (t < 128) tmp[t] = own;
    __syncthreads();
    for (int off = 1; off < 128; off <<= 1) {
        int x = (t >= off && t < 128) ? tmp[t - off] : 0;
        __syncthreads();
        if (t < 128) tmp[t] += x;
        __syncthreads();
    }
    int nodeCnt = min(128, N - node0);
    int sbase = gb + ((t < 128) ? (tmp[t] - own) : 0);
    if (t < nodeCnt) { start[node0 + t] = sbase; endv[node0 + t] = sbase + own; }
    if (t < 128) hist[t] = sbase;          // scatter cursors (global idx)
    __syncthreads();
    for (int i = t; i < cnt; i += 256) {
        unsigned u = (unsigned)ibuf[i];
        int slot = atomicAdd(&hist[u >> 16], 1);
        inter[slot] = u & 0xffffu;          // csr_src write (in place)
    }
}

// ======= layer 1 fused GAT + layer-2 GEMM epilogue (R21) =======
// Edge loop = R20-proven depth-2 pipeline, untouched. Epilogue: post-ELU
// agg stays in LDS (f32); the same wave then computes its dst's 64
// layer-2 outputs (lane = out col, K=128 f32xbf16 FMA vs L2-hot W2T) and
// writes feat2 directly. Kills gemm2 kernel + agg1e buffer + 25.6 MB.
#define GAT1_PROC(U0, U1)                                                     \
    {                                                                         \
        f32x2 f0[4], f1[4];                                                   \
        unpack8v(U0, f0); unpack8v(U1, f1);                                   \
        f32x2 p0 = fd2[0] * f0[0];                                            \
        f32x2 p1 = fd2[0] * f1[0];                                            \
        _Pragma("unroll")                                                     \
        for (int k = 1; k < 4; ++k) { p0 += fd2[k] * f0[k]; p1 += fd2[k] * f1[k]; } \
        float q0 = p0.x + p0.y, q1 = p1.x + p1.y;                             \
        q0 += __shfl_xor(q0, 1); q1 += __shfl_xor(q1, 1);                     \
        float w0 = EXP2(q0), w1 = EXP2(q1);                                   \
        f32x2 W0 = (f32x2){w0, w0}, W1 = (f32x2){w1, w1};                     \
        _Pragma("unroll")                                                     \
        for (int k = 0; k < 4; ++k) { acc2[k] += W0 * f0[k]; acc2[k] += W1 * f1[k]; } \
        l += w0 + w1;                                                         \
    }

__global__ void gat1_kernel(const unsigned short* __restrict__ feat1,
                            const int* __restrict__ csr_src,
                            const int* __restrict__ start,
                            const int* __restrict__ endv,
                            const unsigned short* __restrict__ W2T,
                            unsigned short* __restrict__ feat2, int N) {
    __shared__ float aggl[4][128];
    int widx = threadIdx.x >> 6;
    int wave = blockIdx.x * 4 + widx;
    bool act = wave < N;
    int lane = threadIdx.x & 63;
    int grp = lane >> 4, gl = lane & 15;
    const char* fb = (const char*)feat1;       // uniform base; row = 256 B
    unsigned loff = (unsigned)gl << 4;
    unsigned wrow = act ? ((unsigned)wave << 8) : 0u;
    f32x2 fd2[4];
    unpack8v(*(const uint4*)(fb + (wrow + loff)), fd2);
    const float SC = 0.25f * LOG2E;            // fold score scale + log2e
    const f32x2 SC2 = (f32x2){SC, SC};
#pragma unroll
    for (int k = 0; k < 4; ++k) fd2[k] *= SC2;

    float l = 0.f;
    f32x2 acc2[4];
#pragma unroll
    for (int k = 0; k < 4; ++k) acc2[k] = (f32x2){0.f, 0.f};

    int e0 = act ? start[wave] : 0, e1 = act ? endv[wave] : 0;
    int nfull = (e1 - e0) >> 3;                // full 8-edge iterations
    int base = e0;
    uint4 a0, a1, b0, b1;
    if (nfull > 0) {
        int s0 = csr_src[base + grp];
        int s1 = csr_src[base + 4 + grp];
        a0 = *(const uint4*)(fb + (((unsigned)s0 << 8) + loff));
        a1 = *(const uint4*)(fb + (((unsigned)s1 << 8) + loff));
    }
    if (nfull > 1) {
        int s0 = csr_src[base + 8 + grp];
        int s1 = csr_src[base + 12 + grp];
        b0 = *(const uint4*)(fb + (((unsigned)s0 << 8) + loff));
        b1 = *(const uint4*)(fb + (((unsigned)s1 << 8) + loff));
    }
    for (int it = 0; it + 2 < nfull; ++it) {   // prefetch depth 2
        int nb = base + 16;
        int s0 = csr_src[nb + grp];
        int s1 = csr_src[nb + 4 + grp];
        uint4 n0 = *(const uint4*)(fb + (((unsigned)s0 << 8) + loff));
        uint4 n1 = *(const uint4*)(fb + (((unsigned)s1 << 8) + loff));
        GAT1_PROC(a0, a1);
        a0 = b0; a1 = b1; b0 = n0; b1 = n1;
        base += 8;
    }
    if (nfull > 1) { GAT1_PROC(a0, a1); a0 = b0; a1 = b1; base += 8; }
    if (nfull > 0) { GAT1_PROC(a0, a1); base += 8; }
    for (; base < e1; base += 4) {             // masked tail, 4 edges/step
        int ed = base + grp;
        bool eact = ed < e1;
        int s = eact ? csr_src[ed] : 0;
        uint4 u = *(const uint4*)(fb + (((unsigned)s << 8) + loff));
        f32x2 fv[4]; unpack8v(u, fv);
        f32x2 p = fd2[0] * fv[0];
#pragma unroll
        for (int k = 1; k < 4; ++k) p += fd2[k] * fv[k];
        float q = p.x + p.y;
        q += __shfl_xor(q, 1);
        float w = eact ? EXP2(q) : 0.f;
        f32x2 W = (f32x2){w, w};
#pragma unroll
        for (int k = 0; k < 4; ++k) acc2[k] += W * fv[k];
        l += w;
    }
    // cross-group merge (pure sums)
#pragma unroll
    for (int off = 16; off <= 32; off <<= 1) {
        l += __shfl_xor(l, off);
#pragma unroll
        for (int k = 0; k < 4; ++k) {
            acc2[k].x += __shfl_xor(acc2[k].x, off);
            acc2[k].y += __shfl_xor(acc2[k].y, off);
        }
    }
    if (grp == 0) {
        float rcp = 1.f / fmaxf(l, 1e-9f);
#pragma unroll
        for (int k = 0; k < 4; ++k) {
            float x0 = acc2[k].x * rcp;
            float x1 = acc2[k].y * rcp;
            x0 = (x0 > 0.f) ? x0 : expm1f(x0);   // ELU fused
            x1 = (x1 > 0.f) ? x1 : expm1f(x1);
            aggl[widx][gl * 8 + 2 * k]     = x0;
            aggl[widx][gl * 8 + 2 * k + 1] = x1;
        }
    }
    __syncthreads();
    // ---- fused layer-2 GEMM: this wave's dst row x W2 (128 -> 64) ----
    if (act) {
        const unsigned short* w2row = W2T + lane * WPAD;
        float acc = 0.f;
#pragma unroll
        for (int kb = 0; kb < 128; kb += 8) {
            bf16x8 wv = *(const bf16x8*)(w2row + kb);
            f32x4 aA = *(const f32x4*)&aggl[widx][kb];
            f32x4 aB = *(const f32x4*)&aggl[widx][kb + 4];
            acc += aA[0] * bf16_raw_to_f32((unsigned short)wv[0]);
            acc += aA[1] * bf16_raw_to_f32((unsigned short)wv[1]);
            acc += aA[2] * bf16_raw_to_f32((unsigned short)wv[2]);
            acc += aA[3] * bf16_raw_to_f32((unsigned short)wv[3]);
            acc += aB[0] * bf16_raw_to_f32((unsigned short)wv[4]);
            acc += aB[1] * bf16_raw_to_f32((unsigned short)wv[5]);
            acc += aB[2] * bf16_raw_to_f32((unsigned short)wv[6]);
            acc += aB[3] * bf16_raw_to_f32((unsigned short)wv[7]);
        }
        feat2[(size_t)wave * 64 + lane] = f32_to_bf16_raw(acc);
    }
}

// ======= layer 2 fused GAT (R20-proven, e1 from endv) =======
#define GAT2_PROC(U0, U1)                                                     \
    {                                                                         \
        f32x2 f0[4], f1[4];                                                   \
        unpack8v(U0, f0); unpack8v(U1, f1);                                   \
        f32x2 p0 = fd2[0] * f0[0];                                            \
        f32x2 p1 = fd2[0] * f1[0];                                            \
        _Pragma("unroll")                                                     \
        for (int k = 1; k < 4; ++k) { p0 += fd2[k] * f0[k]; p1 += fd2[k] * f1[k]; } \
        float q0 = p0.x + p0.y, q1 = p1.x + p1.y;                             \
        q0 += __shfl_xor(q0, 1); q1 += __shfl_xor(q1, 1);                     \
        q0 += __shfl_xor(q0, 2); q1 += __shfl_xor(q1, 2);                     \
        q0 += __shfl_xor(q0, 4); q1 += __shfl_xor(q1, 4);                     \
        float w0 = EXP2(q0), w1 = EXP2(q1);                                   \
        f32x2 W0 = (f32x2){w0, w0}, W1 = (f32x2){w1, w1};                     \
        _Pragma("unroll")                                                     \
        for (int k = 0; k < 4; ++k) { acc2[k] += W0 * f0[k]; acc2[k] += W1 * f1[k]; } \
        l += w0 + w1;                                                         \
    }

__global__ void gat2_kernel(const unsigned short* __restrict__ feat2,
                            const int* __restrict__ csr_src,
                            const int* __restrict__ start,
                            const int* __restrict__ endv,
                            void* __restrict__ out, int N,
                            const int* __restrict__ flag) {
    int wave = blockIdx.x * 4 + (threadIdx.x >> 6);
    if (wave >= N) return;
    int lane = threadIdx.x & 63;
    int grp = lane >> 3, gl = lane & 7;
    const int f = *flag;
    const char* fb = (const char*)feat2;       // uniform base; row = 128 B
    unsigned loff = (unsigned)gl << 4;
    f32x2 fd2[4];
    unpack8v(*(const uint4*)(fb + (((unsigned)wave << 7) + loff)), fd2);
    const float SC = 0.125f * LOG2E;
    const f32x2 SC2 = (f32x2){SC, SC};
#pragma unroll
    for (int k = 0; k < 4; ++k) fd2[k] *= SC2;

    float l = 0.f;
    f32x2 acc2[4];
#pragma unroll
    for (int k = 0; k < 4; ++k) acc2[k] = (f32x2){0.f, 0.f};

    int e0 = start[wave], e1 = endv[wave];
    int nfull = (e1 - e0) >> 4;                // full 16-edge iterations
    int base = e0;
    uint4 a0, a1, b0, b1;
    if (nfull > 0) {
        int s0 = csr_src[base + grp];
        int s1 = csr_src[base + 8 + grp];
        a0 = *(const uint4*)(fb + (((unsigned)s0 << 7) + loff));
        a1 = *(const uint4*)(fb + (((unsigned)s1 << 7) + loff));
    }
    if (nfull > 1) {
        int s0 = csr_src[base + 16 + grp];
        int s1 = csr_src[base + 24 + grp];
        b0 = *(const uint4*)(fb + (((unsigned)s0 << 7) + loff));
        b1 = *(const uint4*)(fb + (((unsigned)s1 << 7) + loff));
    }
    for (int it = 0; it + 2 < nfull; ++it) {   // prefetch depth 2
        int nb = base + 32;
        int s0 = csr_src[nb + grp];
        int s1 = csr_src[nb + 8 + grp];
        uint4 n0 = *(const uint4*)(fb + (((unsigned)s0 << 7) + loff));
        uint4 n1 = *(const uint4*)(fb + (((unsigned)s1 << 7) + loff));
        GAT2_PROC(a0, a1);
        a0 = b0; a1 = b1; b0 = n0; b1 = n1;
        base += 16;
    }
    if (nfull > 1) { GAT2_PROC(a0, a1); a0 = b0; a1 = b1; base += 16; }
    if (nfull > 0) { GAT2_PROC(a0, a1); base += 16; }
    for (; base < e1; base += 8) {
        int ed = base + grp;
        bool act = ed < e1;
        int s = act ? csr_src[ed] : 0;
        uint4 u = *(const uint4*)(fb + (((unsigned)s << 7) + loff));
        f32x2 fv[4]; unpack8v(u, fv);
        f32x2 p = fd2[0] * fv[0];
#pragma unroll
        for (int k = 1; k < 4; ++k) p += fd2[k] * fv[k];
        float q = p.x + p.y;
        q += __shfl_xor(q, 1);
        q += __shfl_xor(q, 2);
        q += __shfl_xor(q, 4);
        float w = act ? EXP2(q) : 0.f;
        f32x2 W = (f32x2){w, w};
#pragma unroll
        for (int k = 0; k < 4; ++k) acc2[k] += W * fv[k];
        l += w;
    }
#pragma unroll
    for (int off = 8; off <= 32; off <<= 1) {
        l += __shfl_xor(l, off);
#pragma unroll
        for (int k = 0; k < 4; ++k) {
            acc2[k].x += __shfl_xor(acc2[k].x, off);
            acc2[k].y += __shfl_xor(acc2[k].y, off);
        }
    }
    if (grp == 0) {
        float rcp = 1.f / fmaxf(l, 1e-9f);
        float v[8];
#pragma unroll
        for (int k = 0; k < 4; ++k) {
            v[2 * k]     = acc2[k].x * rcp;
            v[2 * k + 1] = acc2[k].y * rcp;
        }
        if (f) {
            float* op = (float*)out + (size_t)wave * 64 + gl * 8;
            *(float4*)(op)     = (float4){v[0], v[1], v[2], v[3]};
            *(float4*)(op + 4) = (float4){v[4], v[5], v[6], v[7]};
        } else {
            uint4 pk;
            pk.x = (unsigned)f32_to_bf16_raw(v[0]) | ((unsigned)f32_to_bf16_raw(v[1]) << 16);
            pk.y = (unsigned)f32_to_bf16_raw(v[2]) | ((unsigned)f32_to_bf16_raw(v[3]) << 16);
            pk.z = (unsigned)f32_to_bf16_raw(v[4]) | ((unsigned)f32_to_bf16_raw(v[5]) << 16);
            pk.w = (unsigned)f32_to_bf16_raw(v[6]) | ((unsigned)f32_to_bf16_raw(v[7]) << 16);
            *(uint4*)((unsigned short*)out + (size_t)wave * 64 + gl * 8) = pk;
        }
    }
}

extern "C" void kernel_launch(void* const* d_in, const int* in_sizes, int n_in,
                              void* d_out, int out_size, void* d_ws, size_t ws_size,
                              hipStream_t stream) {
    const void* h  = d_in[0];
    const void* W1 = d_in[1];
    const void* W2 = d_in[2];
    const int* src = (const int*)d_in[3];
    const int* dst = (const int*)d_in[4];

    float* ws = (float*)d_ws;
    // Layout (4-byte words), peak ~33 MB (was 45.5).
    unsigned short* feat1 = (unsigned short*)ws;                 // 3.2M words
    unsigned* inter       = (unsigned*)(ws + 3200000);           // 391*CAP = 3.153M words
    int*   csr_src        = (int*)inter;                         // in-place compacted
    unsigned short* feat2 = (unsigned short*)(ws + 6400000);     // 0.8M words
    int*   start          = (int*)(ws + 8000000);                // 50001
    int*   endv           = (int*)(ws + 8060000);                // 50001
    int*   flag           = (int*)(ws + 8120000);
    int*   bcur           = (int*)(ws + 8121000);                // 391 ints
    unsigned short* W1T   = (unsigned short*)(ws + 8130000);
    unsigned short* W2T   = (unsigned short*)(ws + 8140000);

    hipMemsetAsync(bcur, 0, NBUCK2 * sizeof(int), stream);

    // K1: weight prep + dtype flag (13 tiny blocks)
    k1_prep_kernel<<<13, 256, 0, stream>>>(W1, W2, W1T, W2T, flag);

    // K2: binA direct-reserve scatter | gemm1 rows [0, 25024)   (782 blocks)
    k2_binA_gemm1lo_kernel<<<NB_A + G1LO, 256, 0, stream>>>(
        src, dst, bcur, inter, N_EDGES, h, W1T, feat1, N_NODES, flag);

    // K3: binB in-place compact | gemm1 rows [25024, 50000)     (782 blocks)
    k3_binB_gemm1hi_kernel<<<NBUCK2 + G1LO, 256, 0, stream>>>(
        inter, bcur, start, endv, N_NODES, N_EDGES, h, W1T, feat1, flag);

    // gat1 + fused layer-2 GEMM (writes feat2 directly; no agg1e, no gemm2)
    gat1_kernel<<<(N_NODES + 3) / 4, 256, 0, stream>>>(
        feat1, csr_src, start, endv, W2T, feat2, N_NODES);

    gat2_kernel<<<(N_NODES + 3) / 4, 256, 0, stream>>>(
        feat2, csr_src, start, endv, d_out, N_NODES, flag);
}

// Round 10
// 233.092 us; speedup vs baseline: 1.1438x; 1.1438x over previous
//
#include <hip/hip_runtime.h>
#include <hip/hip_bf16.h>

#define N_NODES 50000
#define N_EDGES 1600000
#define EPB 4096              // edges per binning block
#define NB_A ((N_EDGES + EPB - 1) / EPB)   // 391 edge-chunk blocks
#define NBUCK2 391            // ceil(50000/128) buckets of 128 nodes
#define BSHIFT 7
#define BMASK 127
#define CAP 8064              // slots per bucket (mean 4096, sigma 64 -> 62 sigma)

typedef short bf16x8 __attribute__((ext_vector_type(8)));
typedef float f32x4  __attribute__((ext_vector_type(4)));
typedef float f32x2  __attribute__((ext_vector_type(2)));

#if __has_builtin(__builtin_amdgcn_exp2f)
#define EXP2(x) __builtin_amdgcn_exp2f(x)
#else
#define EXP2(x) exp2f(x)
#endif
#define LOG2E 1.44269504088896340736f

__device__ __forceinline__ float bf16_raw_to_f32(unsigned short u) {
    return __uint_as_float(((unsigned)u) << 16);
}
__device__ __forceinline__ unsigned short f32_to_bf16_raw(float v) {
    unsigned u = __float_as_uint(v);
    return (unsigned short)((u + 0x7fffu + ((u >> 16) & 1u)) >> 16);
}
__device__ __forceinline__ float load_elem(const void* p, size_t i, int f) {
    if (f) return ((const float*)p)[i];
    return bf16_raw_to_f32(((const unsigned short*)p)[i]);
}
// unpack 8 bf16 into 4 float2 pairs (pair k = dims {2k, 2k+1})
__device__ __forceinline__ void unpack8v(uint4 u, f32x2* f) {
    f[0] = (f32x2){__uint_as_float(u.x << 16), __uint_as_float(u.x & 0xffff0000u)};
    f[1] = (f32x2){__uint_as_float(u.y << 16), __uint_as_float(u.y & 0xffff0000u)};
    f[2] = (f32x2){__uint_as_float(u.z << 16), __uint_as_float(u.z & 0xffff0000u)};
    f[3] = (f32x2){__uint_as_float(u.w << 16), __uint_as_float(u.w & 0xffff0000u)};
}

// in-block dtype detect (R4-verified heuristic: fp32 storage looks like
// huge/NaN values when read as bf16 pairs).
__device__ __forceinline__ int block_detect(const unsigned short* w1raw) {
    __shared__ float red[256];
    int t = threadIdx.x;
    float mx = 0.f;
    for (int i = t * 2; i < 16384; i += 512) {
        float v = fabsf(bf16_raw_to_f32(w1raw[i]));
        if (!isnan(v)) mx = fmaxf(mx, v);
    }
    red[t] = mx;
    __syncthreads();
    for (int s = 128; s > 0; s >>= 1) {
        if (t < s) red[t] = fmaxf(red[t], red[t + s]);
        __syncthreads();
    }
    return (red[0] > 1e4f) ? 1 : 0;
}

#define WPAD 136

// ===== K1: prep (12 blocks) + detect (1 block) — tiny =====
__global__ void k1_prep_kernel(const void* __restrict__ W1,
                               const void* __restrict__ W2,
                               unsigned short* __restrict__ W1T,
                               unsigned short* __restrict__ W2T,
                               int* __restrict__ flag) {
    int bid = blockIdx.x;
    if (bid < 12) {
        const int f = block_detect((const unsigned short*)W1);
        int tid = threadIdx.x;
        if (bid < 8) {
            int n = bid * 16 + (tid & 15);
            int kb = (tid >> 4) * 8;
            for (int j = 0; j < 8; ++j)
                W1T[n * WPAD + kb + j] = f32_to_bf16_raw(load_elem(W1, (size_t)(kb + j) * 128 + n, f));
        } else {
            int n = (bid - 8) * 16 + (tid & 15);
            int kb = (tid >> 4) * 8;
            for (int j = 0; j < 8; ++j)
                W2T[n * WPAD + kb + j] = f32_to_bf16_raw(load_elem(W2, (size_t)(kb + j) * 64 + n, f));
        }
    } else {
        int f = block_detect((const unsigned short*)W1);
        if (threadIdx.x == 0) flag[0] = f;
    }
}

// ---- MFMA GEMM1 body (R9-proven), with row base for split launches ----
__device__ __forceinline__ void gemm1_body(const void* __restrict__ h,
                                           const unsigned short* __restrict__ W1T,
                                           unsigned short* __restrict__ feat1, int N,
                                           int f, int blk, int row_base) {
    int lane = threadIdx.x & 63;
    int rbase = row_base + blk * 64 + (threadIdx.x >> 6) * 16;
    int arow = rbase + (lane & 15);
    int arowc = min(arow, N - 1);
    int kb0 = (lane >> 4) * 8;

    f32x4 acc[8];
#pragma unroll
    for (int t = 0; t < 8; ++t) acc[t] = (f32x4){0.f, 0.f, 0.f, 0.f};

#pragma unroll
    for (int ks = 0; ks < 4; ++ks) {
        int kb = ks * 32 + kb0;
        bf16x8 afrag;
        if (f == 0) {
            afrag = *(const bf16x8*)((const unsigned short*)h + (size_t)arowc * 128 + kb);
        } else {
            const float* hp = (const float*)h + (size_t)arowc * 128 + kb;
#pragma unroll
            for (int j = 0; j < 8; ++j) afrag[j] = (short)f32_to_bf16_raw(hp[j]);
        }
#pragma unroll
        for (int t = 0; t < 8; ++t) {
            int n = t * 16 + (lane & 15);
            bf16x8 bfrag = *(const bf16x8*)(W1T + n * WPAD + kb);
            acc[t] = __builtin_amdgcn_mfma_f32_16x16x32_bf16(afrag, bfrag, acc[t], 0, 0, 0);
        }
    }
    int orow0 = rbase + (lane >> 4) * 4;
    int col = lane & 15;
#pragma unroll
    for (int t = 0; t < 8; ++t)
#pragma unroll
        for (int r = 0; r < 4; ++r) {
            int row = orow0 + r;
            if (row < N)
                feat1[(size_t)row * 128 + t * 16 + col] = f32_to_bf16_raw(acc[t][r]);
        }
}

#define G1LO 391                   // gemm1 blocks covering rows [0, 25024)
#define G1OFF (G1LO * 64)          // 25024

// ===== K2: fused [binA direct-reserve (391) | gemm1 rows 0..25023 (391)] =====
__global__ void k2_binA_gemm1lo_kernel(const int* __restrict__ src,
                                       const int* __restrict__ dst,
                                       int* __restrict__ bcur,
                                       unsigned* __restrict__ inter, int E,
                                       const void* __restrict__ h,
                                       const unsigned short* __restrict__ W1T,
                                       unsigned short* __restrict__ feat1, int N,
                                       const int* __restrict__ flag) {
    int bid = blockIdx.x;
    if (bid >= NB_A) {
        gemm1_body(h, W1T, feat1, N, *flag, bid - NB_A, 0);
        return;
    }
    __shared__ int hist[NBUCK2], gbase[NBUCK2], cur[NBUCK2];
    int t = threadIdx.x;
    for (int i = t; i < NBUCK2; i += 256) { hist[i] = 0; cur[i] = 0; }
    __syncthreads();
    int e0 = bid * EPB;
    for (int k = 0; k < 16; ++k) {
        int e = e0 + k * 256 + t;
        if (e < E) atomicAdd(&hist[dst[e] >> BSHIFT], 1);
    }
    __syncthreads();
    // direct slot reservation: bucket b occupies [b*CAP, (b+1)*CAP)
    for (int i = t; i < NBUCK2; i += 256) {
        int hv = hist[i];
        gbase[i] = hv ? (i * CAP + atomicAdd(&bcur[i], hv)) : 0;
    }
    __syncthreads();
    for (int k = 0; k < 16; ++k) {
        int e = e0 + k * 256 + t;
        if (e < E) {
            int d = dst[e];
            int b = d >> BSHIFT;
            int off = atomicAdd(&cur[b], 1);
            int slot = gbase[b] + off;
            if (slot < (b + 1) * CAP)   // overflow clamp (62-sigma, never in practice)
                inter[slot] = (unsigned)src[e] | ((unsigned)(d & BMASK) << 16);
        }
    }
}

// ===== K3: fused [binB in-place compact (391) | gemm1 rows 25024.. (391)] =====
__global__ void k3_binB_gemm1hi_kernel(unsigned* __restrict__ inter,   // also csr out
                                       const int* __restrict__ bcur,
                                       int* __restrict__ start,
                                       int* __restrict__ endv,
                                       int N, int E,
                                       const void* __restrict__ h,
                                       const unsigned short* __restrict__ W1T,
                                       unsigned short* __restrict__ feat1,
                                       const int* __restrict__ flag) {
    int bid = blockIdx.x;
    if (bid >= NBUCK2) {
        gemm1_body(h, W1T, feat1, N, *flag, bid - NBUCK2, G1OFF);
        return;
    }
    int b = bid;
    int node0 = b << BSHIFT;
    __shared__ int ibuf[CAP];
    __shared__ int hist[128];
    __shared__ int tmp[128];
    int t = threadIdx.x;
    int cnt = min(bcur[b], CAP);
    int gb = b * CAP;
    // stage bucket into LDS (enables in-place compaction: csr aliases inter)
    for (int i = t; i < cnt; i += 256) ibuf[i] = (int)inter[gb + i];
    if (t < 128) hist[t] = 0;
    __syncthreads();
    for (int i = t; i < cnt; i += 256) atomicAdd(&hist[((unsigned)ibuf[i]) >> 16], 1);
    __syncthreads();
    int own = (t < 128) ? hist[t] : 0;
    if (t < 128) tmp[t] = own;
    __syncthreads();
    for (int off = 1; off < 128; off <<= 1) {
        int x = (t >= off && t < 128) ? tmp[t - off] : 0;
        __syncthreads();
        if (t < 128) tmp[t] += x;
        __syncthreads();
    }
    int nodeCnt = min(128, N - node0);
    int sbase = gb + ((t < 128) ? (tmp[t] - own) : 0);
    if (t < nodeCnt) { start[node0 + t] = sbase; endv[node0 + t] = sbase + own; }
    if (t < 128) hist[t] = sbase;          // scatter cursors (global idx)
    __syncthreads();
    for (int i = t; i < cnt; i += 256) {
        unsigned u = (unsigned)ibuf[i];
        int slot = atomicAdd(&hist[u >> 16], 1);
        inter[slot] = u & 0xffffu;          // csr_src write (in place)
    }
}

// ---- MFMA GEMM2 (R9-proven; restored — R21's scalar fusion cost +36us) ----
__global__ void gemm2_mfma_kernel(const unsigned short* __restrict__ agg1e,
                                  const unsigned short* __restrict__ W2T,
                                  unsigned short* __restrict__ feat2, int N) {
    int lane = threadIdx.x & 63;
    int rbase = blockIdx.x * 64 + (threadIdx.x >> 6) * 16;
    int arow = rbase + (lane & 15);
    int arowc = min(arow, N - 1);
    int kb0 = (lane >> 4) * 8;

    f32x4 acc[4];
#pragma unroll
    for (int t = 0; t < 4; ++t) acc[t] = (f32x4){0.f, 0.f, 0.f, 0.f};

#pragma unroll
    for (int ks = 0; ks < 4; ++ks) {
        int kb = ks * 32 + kb0;
        bf16x8 afrag = *(const bf16x8*)(agg1e + (size_t)arowc * 128 + kb);
#pragma unroll
        for (int t = 0; t < 4; ++t) {
            int n = t * 16 + (lane & 15);
            bf16x8 bfrag = *(const bf16x8*)(W2T + n * WPAD + kb);
            acc[t] = __builtin_amdgcn_mfma_f32_16x16x32_bf16(afrag, bfrag, acc[t], 0, 0, 0);
        }
    }
    int orow0 = rbase + (lane >> 4) * 4;
    int col = lane & 15;
#pragma unroll
    for (int t = 0; t < 4; ++t)
#pragma unroll
        for (int r = 0; r < 4; ++r) {
            int row = orow0 + r;
            if (row < N)
                feat2[(size_t)row * 64 + t * 16 + col] = f32_to_bf16_raw(acc[t][r]);
        }
}

// ======= layer 1 fused GAT (R20-proven form; endv[] for edge range) =======
#define GAT1_PROC(U0, U1)                                                     \
    {                                                                         \
        f32x2 f0[4], f1[4];                                                   \
        unpack8v(U0, f0); unpack8v(U1, f1);                                   \
        f32x2 p0 = fd2[0] * f0[0];                                            \
        f32x2 p1 = fd2[0] * f1[0];                                            \
        _Pragma("unroll")                                                     \
        for (int k = 1; k < 4; ++k) { p0 += fd2[k] * f0[k]; p1 += fd2[k] * f1[k]; } \
        float q0 = p0.x + p0.y, q1 = p1.x + p1.y;                             \
        q0 += __shfl_xor(q0, 1); q1 += __shfl_xor(q1, 1);                     \
        float w0 = EXP2(q0), w1 = EXP2(q1);                                   \
        f32x2 W0 = (f32x2){w0, w0}, W1 = (f32x2){w1, w1};                     \
        _Pragma("unroll")                                                     \
        for (int k = 0; k < 4; ++k) { acc2[k] += W0 * f0[k]; acc2[k] += W1 * f1[k]; } \
        l += w0 + w1;                                                         \
    }

__global__ void gat1_kernel(const unsigned short* __restrict__ feat1,
                            const int* __restrict__ csr_src,
                            const int* __restrict__ start,
                            const int* __restrict__ endv,
                            unsigned short* __restrict__ agg1e, int N) {
    int wave = blockIdx.x * 4 + (threadIdx.x >> 6);
    if (wave >= N) return;
    int lane = threadIdx.x & 63;
    int grp = lane >> 4, gl = lane & 15;
    const char* fb = (const char*)feat1;       // uniform base; row = 256 B
    unsigned loff = (unsigned)gl << 4;
    f32x2 fd2[4];
    unpack8v(*(const uint4*)(fb + (((unsigned)wave << 8) + loff)), fd2);
    const float SC = 0.25f * LOG2E;            // fold score scale + log2e
    const f32x2 SC2 = (f32x2){SC, SC};
#pragma unroll
    for (int k = 0; k < 4; ++k) fd2[k] *= SC2;

    float l = 0.f;
    f32x2 acc2[4];
#pragma unroll
    for (int k = 0; k < 4; ++k) acc2[k] = (f32x2){0.f, 0.f};

    int e0 = start[wave], e1 = endv[wave];
    int nfull = (e1 - e0) >> 3;                // full 8-edge iterations
    int base = e0;
    uint4 a0, a1, b0, b1;
    if (nfull > 0) {
        int s0 = csr_src[base + grp];
        int s1 = csr_src[base + 4 + grp];
        a0 = *(const uint4*)(fb + (((unsigned)s0 << 8) + loff));
        a1 = *(const uint4*)(fb + (((unsigned)s1 << 8) + loff));
    }
    if (nfull > 1) {
        int s0 = csr_src[base + 8 + grp];
        int s1 = csr_src[base + 12 + grp];
        b0 = *(const uint4*)(fb + (((unsigned)s0 << 8) + loff));
        b1 = *(const uint4*)(fb + (((unsigned)s1 << 8) + loff));
    }
    for (int it = 0; it + 2 < nfull; ++it) {   // prefetch depth 2
        int nb = base + 16;
        int s0 = csr_src[nb + grp];
        int s1 = csr_src[nb + 4 + grp];
        uint4 n0 = *(const uint4*)(fb + (((unsigned)s0 << 8) + loff));
        uint4 n1 = *(const uint4*)(fb + (((unsigned)s1 << 8) + loff));
        GAT1_PROC(a0, a1);
        a0 = b0; a1 = b1; b0 = n0; b1 = n1;
        base += 8;
    }
    if (nfull > 1) { GAT1_PROC(a0, a1); a0 = b0; a1 = b1; base += 8; }
    if (nfull > 0) { GAT1_PROC(a0, a1); base += 8; }
    for (; base < e1; base += 4) {             // masked tail, 4 edges/step
        int ed = base + grp;
        bool act = ed < e1;
        int s = act ? csr_src[ed] : 0;
        uint4 u = *(const uint4*)(fb + (((unsigned)s << 8) + loff));
        f32x2 fv[4]; unpack8v(u, fv);
        f32x2 p = fd2[0] * fv[0];
#pragma unroll
        for (int k = 1; k < 4; ++k) p += fd2[k] * fv[k];
        float q = p.x + p.y;
        q += __shfl_xor(q, 1);
        float w = act ? EXP2(q) : 0.f;
        f32x2 W = (f32x2){w, w};
#pragma unroll
        for (int k = 0; k < 4; ++k) acc2[k] += W * fv[k];
        l += w;
    }
    // cross-group merge (pure sums)
#pragma unroll
    for (int off = 16; off <= 32; off <<= 1) {
        l += __shfl_xor(l, off);
#pragma unroll
        for (int k = 0; k < 4; ++k) {
            acc2[k].x += __shfl_xor(acc2[k].x, off);
            acc2[k].y += __shfl_xor(acc2[k].y, off);
        }
    }
    if (grp == 0) {
        float rcp = 1.f / fmaxf(l, 1e-9f);
        float v[8];
#pragma unroll
        for (int k = 0; k < 4; ++k) {
            float x0 = acc2[k].x * rcp;
            float x1 = acc2[k].y * rcp;
            v[2 * k]     = (x0 > 0.f) ? x0 : expm1f(x0);   // ELU fused
            v[2 * k + 1] = (x1 > 0.f) ? x1 : expm1f(x1);
        }
        uint4 pk;
        pk.x = (unsigned)f32_to_bf16_raw(v[0]) | ((unsigned)f32_to_bf16_raw(v[1]) << 16);
        pk.y = (unsigned)f32_to_bf16_raw(v[2]) | ((unsigned)f32_to_bf16_raw(v[3]) << 16);
        pk.z = (unsigned)f32_to_bf16_raw(v[4]) | ((unsigned)f32_to_bf16_raw(v[5]) << 16);
        pk.w = (unsigned)f32_to_bf16_raw(v[6]) | ((unsigned)f32_to_bf16_raw(v[7]) << 16);
        *(uint4*)(agg1e + (size_t)wave * 128 + gl * 8) = pk;
    }
}

// ======= layer 2 fused GAT (R20-proven, e1 from endv) =======
#define GAT2_PROC(U0, U1)                                                     \
    {                                                                         \
        f32x2 f0[4], f1[4];                                                   \
        unpack8v(U0, f0); unpack8v(U1, f1);                                   \
        f32x2 p0 = fd2[0] * f0[0];                                            \
        f32x2 p1 = fd2[0] * f1[0];                                            \
        _Pragma("unroll")                                                     \
        for (int k = 1; k < 4; ++k) { p0 += fd2[k] * f0[k]; p1 += fd2[k] * f1[k]; } \
        float q0 = p0.x + p0.y, q1 = p1.x + p1.y;                             \
        q0 += __shfl_xor(q0, 1); q1 += __shfl_xor(q1, 1);                     \
        q0 += __shfl_xor(q0, 2); q1 += __shfl_xor(q1, 2);                     \
        q0 += __shfl_xor(q0, 4); q1 += __shfl_xor(q1, 4);                     \
        float w0 = EXP2(q0), w1 = EXP2(q1);                                   \
        f32x2 W0 = (f32x2){w0, w0}, W1 = (f32x2){w1, w1};                     \
        _Pragma("unroll")                                                     \
        for (int k = 0; k < 4; ++k) { acc2[k] += W0 * f0[k]; acc2[k] += W1 * f1[k]; } \
        l += w0 + w1;                                                         \
    }

__global__ void gat2_kernel(const unsigned short* __restrict__ feat2,
                            const int* __restrict__ csr_src,
                            const int* __restrict__ start,
                            const int* __restrict__ endv,
                            void* __restrict__ out, int N,
                            const int* __restrict__ flag) {
    int wave = blockIdx.x * 4 + (threadIdx.x >> 6);
    if (wave >= N) return;
    int lane = threadIdx.x & 63;
    int grp = lane >> 3, gl = lane & 7;
    const int f = *flag;
    const char* fb = (const char*)feat2;       // uniform base; row = 128 B
    unsigned loff = (unsigned)gl << 4;
    f32x2 fd2[4];
    unpack8v(*(const uint4*)(fb + (((unsigned)wave << 7) + loff)), fd2);
    const float SC = 0.125f * LOG2E;
    const f32x2 SC2 = (f32x2){SC, SC};
#pragma unroll
    for (int k = 0; k < 4; ++k) fd2[k] *= SC2;

    float l = 0.f;
    f32x2 acc2[4];
#pragma unroll
    for (int k = 0; k < 4; ++k) acc2[k] = (f32x2){0.f, 0.f};

    int e0 = start[wave], e1 = endv[wave];
    int nfull = (e1 - e0) >> 4;                // full 16-edge iterations
    int base = e0;
    uint4 a0, a1, b0, b1;
    if (nfull > 0) {
        int s0 = csr_src[base + grp];
        int s1 = csr_src[base + 8 + grp];
        a0 = *(const uint4*)(fb + (((unsigned)s0 << 7) + loff));
        a1 = *(const uint4*)(fb + (((unsigned)s1 << 7) + loff));
    }
    if (nfull > 1) {
        int s0 = csr_src[base + 16 + grp];
        int s1 = csr_src[base + 24 + grp];
        b0 = *(const uint4*)(fb + (((unsigned)s0 << 7) + loff));
        b1 = *(const uint4*)(fb + (((unsigned)s1 << 7) + loff));
    }
    for (int it = 0; it + 2 < nfull; ++it) {   // prefetch depth 2
        int nb = base + 32;
        int s0 = csr_src[nb + grp];
        int s1 = csr_src[nb + 8 + grp];
        uint4 n0 = *(const uint4*)(fb + (((unsigned)s0 << 7) + loff));
        uint4 n1 = *(const uint4*)(fb + (((unsigned)s1 << 7) + loff));
        GAT2_PROC(a0, a1);
        a0 = b0; a1 = b1; b0 = n0; b1 = n1;
        base += 16;
    }
    if (nfull > 1) { GAT2_PROC(a0, a1); a0 = b0; a1 = b1; base += 16; }
    if (nfull > 0) { GAT2_PROC(a0, a1); base += 16; }
    for (; base < e1; base += 8) {
        int ed = base + grp;
        bool act = ed < e1;
        int s = act ? csr_src[ed] : 0;
        uint4 u = *(const uint4*)(fb + (((unsigned)s << 7) + loff));
        f32x2 fv[4]; unpack8v(u, fv);
        f32x2 p = fd2[0] * fv[0];
#pragma unroll
        for (int k = 1; k < 4; ++k) p += fd2[k] * fv[k];
        float q = p.x + p.y;
        q += __shfl_xor(q, 1);
        q += __shfl_xor(q, 2);
        q += __shfl_xor(q, 4);
        float w = act ? EXP2(q) : 0.f;
        f32x2 W = (f32x2){w, w};
#pragma unroll
        for (int k = 0; k < 4; ++k) acc2[k] += W * fv[k];
        l += w;
    }
#pragma unroll
    for (int off = 8; off <= 32; off <<= 1) {
        l += __shfl_xor(l, off);
#pragma unroll
        for (int k = 0; k < 4; ++k) {
            acc2[k].x += __shfl_xor(acc2[k].x, off);
            acc2[k].y += __shfl_xor(acc2[k].y, off);
        }
    }
    if (grp == 0) {
        float rcp = 1.f / fmaxf(l, 1e-9f);
        float v[8];
#pragma unroll
        for (int k = 0; k < 4; ++k) {
            v[2 * k]     = acc2[k].x * rcp;
            v[2 * k + 1] = acc2[k].y * rcp;
        }
        if (f) {
            float* op = (float*)out + (size_t)wave * 64 + gl * 8;
            *(float4*)(op)     = (float4){v[0], v[1], v[2], v[3]};
            *(float4*)(op + 4) = (float4){v[4], v[5], v[6], v[7]};
        } else {
            uint4 pk;
            pk.x = (unsigned)f32_to_bf16_raw(v[0]) | ((unsigned)f32_to_bf16_raw(v[1]) << 16);
            pk.y = (unsigned)f32_to_bf16_raw(v[2]) | ((unsigned)f32_to_bf16_raw(v[3]) << 16);
            pk.z = (unsigned)f32_to_bf16_raw(v[4]) | ((unsigned)f32_to_bf16_raw(v[5]) << 16);
            pk.w = (unsigned)f32_to_bf16_raw(v[6]) | ((unsigned)f32_to_bf16_raw(v[7]) << 16);
            *(uint4*)((unsigned short*)out + (size_t)wave * 64 + gl * 8) = pk;
        }
    }
}

extern "C" void kernel_launch(void* const* d_in, const int* in_sizes, int n_in,
                              void* d_out, int out_size, void* d_ws, size_t ws_size,
                              hipStream_t stream) {
    const void* h  = d_in[0];
    const void* W1 = d_in[1];
    const void* W2 = d_in[2];
    const int* src = (const int*)d_in[3];
    const int* dst = (const int*)d_in[4];

    float* ws = (float*)d_ws;
    // Layout (4-byte words), peak ~45 MB.
    unsigned short* feat1 = (unsigned short*)ws;                 // 3.2M words
    unsigned* inter       = (unsigned*)(ws + 3200000);           // 391*CAP = 3.153M words
    int*   csr_src        = (int*)inter;                         // in-place compacted
    unsigned short* agg1e = (unsigned short*)(ws + 6400000);     // 3.2M words
    unsigned short* feat2 = (unsigned short*)(ws + 9600000);     // 1.6M words
    int*   start          = (int*)(ws + 11200000);               // 50001
    int*   endv           = (int*)(ws + 11260000);               // 50001
    int*   flag           = (int*)(ws + 11330000);
    int*   bcur           = (int*)(ws + 11331000);               // 391 ints
    unsigned short* W1T   = (unsigned short*)(ws + 11340000);
    unsigned short* W2T   = (unsigned short*)(ws + 11350000);

    hipMemsetAsync(bcur, 0, NBUCK2 * sizeof(int), stream);

    // K1: weight prep + dtype flag (13 tiny blocks)
    k1_prep_kernel<<<13, 256, 0, stream>>>(W1, W2, W1T, W2T, flag);

    // K2: binA direct-reserve scatter | gemm1 rows [0, 25024)   (782 blocks)
    k2_binA_gemm1lo_kernel<<<NB_A + G1LO, 256, 0, stream>>>(
        src, dst, bcur, inter, N_EDGES, h, W1T, feat1, N_NODES, flag);

    // K3: binB in-place compact | gemm1 rows [25024, 50000)     (782 blocks)
    k3_binB_gemm1hi_kernel<<<NBUCK2 + G1LO, 256, 0, stream>>>(
        inter, bcur, start, endv, N_NODES, N_EDGES, h, W1T, feat1, flag);

    gat1_kernel<<<(N_NODES + 3) / 4, 256, 0, stream>>>(
        feat1, csr_src, start, endv, agg1e, N_NODES);
    gemm2_mfma_kernel<<<(N_NODES + 63) / 64, 256, 0, stream>>>(
        agg1e, W2T, feat2, N_NODES);
    gat2_kernel<<<(N_NODES + 3) / 4, 256, 0, stream>>>(
        feat2, csr_src, start, endv, d_out, N_NODES, flag);
}